// Round 1
// 9605.481 us; speedup vs baseline: 1.3863x; 1.3863x over previous
//
#include <hip/hip_runtime.h>
#include <cmath>

#define NB 8      // batch
#define NT 256    // seq len
#define NE 512    // embed
#define NF 2048   // ffn
#define NV 32000  // vocab
#define ND 256    // mem dim
#define NN 2048   // mem slots
#define NL 2
#define NHM 4     // mem heads
#define NHD 64
#define NHA 8     // attn heads
#define NIF 1028
#define NMT (NB*NT)

typedef __bf16 bf16x8 __attribute__((ext_vector_type(8)));
typedef float floatx4 __attribute__((ext_vector_type(4)));
typedef unsigned short u16x8 __attribute__((ext_vector_type(8)));

__device__ __forceinline__ unsigned short f2bf(float f){
  unsigned u = __float_as_uint(f);
  u += 0x7fffu + ((u>>16)&1u);
  return (unsigned short)(u>>16);
}
__device__ __forceinline__ float bf2f(unsigned short h){
  return __uint_as_float(((unsigned)h)<<16);
}

// ---- transpose+convert: out[n*ldo + k] = bf16(in[k*N + n]) ----
__global__ __launch_bounds__(256)
void k_tcvt(const float* __restrict__ in, int K, int N,
            unsigned short* __restrict__ out, int ldo)
{
  __shared__ float tile[32][33];
  int n0 = blockIdx.x<<5, k0 = blockIdx.y<<5;
  int tx = threadIdx.x & 31, ty = threadIdx.x >> 5;
  #pragma unroll
  for (int i=0;i<4;i++){
    int k = k0 + (ty<<2) + i, n = n0 + tx;
    tile[(ty<<2)+i][tx] = (k<K && n<N) ? in[(size_t)k*N + n] : 0.f;
  }
  __syncthreads();
  #pragma unroll
  for (int i=0;i<4;i++){
    int n = n0 + (ty<<2) + i, k = k0 + tx;
    if (n<N && k<K) out[(size_t)n*ldo + k] = f2bf(tile[tx][(ty<<2)+i]);
  }
}

__global__ void k_embed(const int* __restrict__ ids, const float* __restrict__ emb,
                        const float* __restrict__ pos, float* __restrict__ x)
{
  int i = blockIdx.x*blockDim.x + threadIdx.x;
  if (i >= NMT*NE) return;
  int e = i & (NE-1); int row = i >> 9; int t = row & (NT-1);
  x[i] = emb[(size_t)ids[row]*NE + e] + pos[t*NE + e];
}

__global__ void k_initmem(const float* __restrict__ mi, float* __restrict__ mem)
{
  int i = blockIdx.x*blockDim.x + threadIdx.x;
  if (i >= NB*NHM*NN*NHD) return;
  int d = i & 63; int n = (i>>6) & (NN-1); int h = (i>>17) & 3;
  mem[i] = mi[n*ND + h*64 + d];
}

// one wave per row of 512
__global__ __launch_bounds__(256)
void k_ln(const float* __restrict__ x, const float* __restrict__ g,
          const float* __restrict__ bb, unsigned short* __restrict__ out)
{
  int row = (blockIdx.x<<2) + (threadIdx.x>>6);
  int lane = threadIdx.x & 63;
  const float* xr = x + (size_t)row*NE;
  float v[8]; float s = 0.f;
  #pragma unroll
  for (int m=0;m<8;m++){ v[m] = xr[lane + (m<<6)]; s += v[m]; }
  #pragma unroll
  for (int o=32;o;o>>=1) s += __shfl_xor(s,o);
  float mean = s * (1.f/NE);
  float vs = 0.f;
  #pragma unroll
  for (int m=0;m<8;m++){ float d=v[m]-mean; vs += d*d; }
  #pragma unroll
  for (int o=32;o;o>>=1) vs += __shfl_xor(vs,o);
  float rstd = rsqrtf(vs*(1.f/NE) + 1e-5f);
  #pragma unroll
  for (int m=0;m<8;m++){
    int e = lane + (m<<6);
    out[(size_t)row*NE + e] = f2bf((v[m]-mean)*rstd*g[e] + bb[e]);
  }
}

// ---- GEMM: C[M,N] = A[M,K] @ BT[N,K]^T, bf16 in / fp32 acc, 128x128 tile ----
__global__ __launch_bounds__(256,2)
void k_gemm(const unsigned short* __restrict__ A, const unsigned short* __restrict__ BT,
            int M, int N, int K,
            float* __restrict__ Cf, unsigned short* __restrict__ Cb,
            const float* __restrict__ bias, const float* __restrict__ addsrc, int gelu)
{
  __shared__ __align__(16) unsigned short As[128*40];
  __shared__ __align__(16) unsigned short Bs[128*40];
  const int tid = threadIdx.x;
  const int lane = tid & 63, wave = tid >> 6;
  const int wm = wave >> 1, wn = wave & 1;
  const int l15 = lane & 15, qd = lane >> 4;
  const int rowA0 = blockIdx.x*128, rowB0 = blockIdx.y*128;

  floatx4 acc[4][4];
  #pragma unroll
  for (int i=0;i<4;i++)
    #pragma unroll
    for (int j=0;j<4;j++) acc[i][j] = 0.f;

  for (int k0=0; k0<K; k0+=32){
    #pragma unroll
    for (int it=0; it<2; it++){
      int c = tid + (it<<8);
      int r = c >> 2, c16 = c & 3;
      uint4 va = *(const uint4*)(A + (size_t)(rowA0+r)*K + k0 + (c16<<3));
      *(uint4*)(&As[r*40 + (c16<<3)]) = va;
      int rn = rowB0 + r; if (rn > N-1) rn = N-1;
      uint4 vb = *(const uint4*)(BT + (size_t)rn*K + k0 + (c16<<3));
      *(uint4*)(&Bs[r*40 + (c16<<3)]) = vb;
    }
    __syncthreads();
    bf16x8 af[4], bfv[4];
    #pragma unroll
    for (int i=0;i<4;i++)
      af[i] = *(const bf16x8*)(&As[(wm*64 + i*16 + l15)*40 + (qd<<3)]);
    #pragma unroll
    for (int j=0;j<4;j++)
      bfv[j] = *(const bf16x8*)(&Bs[(wn*64 + j*16 + l15)*40 + (qd<<3)]);
    #pragma unroll
    for (int i=0;i<4;i++)
      #pragma unroll
      for (int j=0;j<4;j++)
        acc[i][j] = __builtin_amdgcn_mfma_f32_16x16x32_bf16(af[i], bfv[j], acc[i][j], 0, 0, 0);
    __syncthreads();
  }
  #pragma unroll
  for (int i=0;i<4;i++){
    #pragma unroll
    for (int j=0;j<4;j++){
      int col = rowB0 + wn*64 + j*16 + l15;
      if (col < N){
        float bsv = bias ? bias[col] : 0.f;
        #pragma unroll
        for (int r4=0;r4<4;r4++){
          int row = rowA0 + wm*64 + i*16 + (qd<<2) + r4;
          float v = acc[i][j][r4] + bsv;
          if (gelu){
            float xx = v;
            v = 0.5f*xx*(1.f + tanhf(0.7978845608028654f*(xx + 0.044715f*xx*xx*xx)));
          }
          if (addsrc) v += addsrc[(size_t)row*N + col];
          if (Cf) Cf[(size_t)row*N + col] = v;
          if (Cb) Cb[(size_t)row*N + col] = f2bf(v);
        }
      }
    }
  }
}

// ---- causal attention, one block per (b, head, q-tile of 64); K/V bf16 in 64KB LDS ----
__global__ __launch_bounds__(256)
void k_attn(const float* __restrict__ qkv, unsigned short* __restrict__ ob)
{
  __shared__ unsigned short Ksh[256*64];   // XOR-swizzled columns
  __shared__ unsigned short Vsh[256*64];
  const int blk = blockIdx.x;
  const int qt = blk & 3, bh = blk >> 2;
  const int h = bh & 7, b = bh >> 3;
  const int lane = threadIdx.x & 63, wave = threadIdx.x >> 6;
  for (int tk = wave; tk < 256; tk += 4){
    size_t base = ((size_t)(b*NT + tk))*1536 + h*64 + lane;
    int sw = lane ^ ((tk<<1)&62);
    Ksh[tk*64 + sw]   = f2bf(qkv[base + 512]);
    Vsh[tk*64 + lane] = f2bf(qkv[base + 1024]);
  }
  __syncthreads();
  const int xm = (lane<<1)&62;
  for (int r=0;r<16;r++){
    int tq = qt*64 + wave*16 + r;
    float qreg = qkv[((size_t)(b*NT + tq))*1536 + h*64 + lane];
    int cmax = tq >> 6;
    float sarr[4] = {-1e30f,-1e30f,-1e30f,-1e30f};
    #pragma unroll
    for (int c=0;c<4;c++){
      if (c <= cmax){
        int tk = (c<<6) + lane;
        float a = 0.f;
        #pragma unroll 16
        for (int d=0; d<64; d++){
          float qd2 = __shfl(qreg, d);
          a += qd2 * bf2f(Ksh[tk*64 + (d ^ xm)]);
        }
        sarr[c] = (tk <= tq) ? a*0.125f : -1e30f;
      }
    }
    float m = fmaxf(fmaxf(sarr[0],sarr[1]), fmaxf(sarr[2],sarr[3]));
    #pragma unroll
    for (int o=32;o;o>>=1) m = fmaxf(m, __shfl_xor(m,o));
    float p[4]; float sum = 0.f;
    #pragma unroll
    for (int c=0;c<4;c++){ p[c] = (sarr[c] > -1e29f) ? __expf(sarr[c]-m) : 0.f; sum += p[c]; }
    #pragma unroll
    for (int o=32;o;o>>=1) sum += __shfl_xor(sum,o);
    float inv = 1.f/sum;
    #pragma unroll
    for (int c=0;c<4;c++) p[c] *= inv;
    float oacc = 0.f;
    #pragma unroll
    for (int c=0;c<4;c++){
      if (c <= cmax){
        int jmax = tq - (c<<6); if (jmax > 63) jmax = 63;
        for (int jj=0; jj<=jmax; jj++){
          float pj = __shfl(p[c], jj);
          oacc += pj * bf2f(Vsh[((c<<6)+jj)*64 + lane]);
        }
      }
    }
    ob[((size_t)(b*NT + tq))*NE + h*64 + lane] = f2bf(oacc);
  }
}

// ---- persistent memory-network scan: 32 blocks = (b, mem-head), 1024 threads,
//      256 steps, one 4-block (per-batch) device barrier per step ----
// WifrT is TRANSPOSED: WifrT[c*256 + e] = W_if_r[e][c]  (bf16)
__global__ __launch_bounds__(1024)
void k_scan(const float* __restrict__ iface, const unsigned short* __restrict__ WifrT,
            const float* __restrict__ b_if, const float* __restrict__ betaRp,
            const float* __restrict__ betaWp, float* __restrict__ mem,
            float* __restrict__ rvs, unsigned int* __restrict__ bar)
{
  __shared__ float rv_s[ND];
  __shared__ float part_lds[4][256];
  __shared__ float islice[256];          // [g*64+d] g: 0=rk 1=wk 2=wv 3=er
  __shared__ float knr[64], knw[64], es_s[64];
  __shared__ float g_s, grraw_s;
  __shared__ float simR[NN], simW[NN];
  __shared__ float rnorm[NN];            // cached 1/||mem_row||
  __shared__ float c8v[4][8];            // per-wave sorted top-8 values
  __shared__ int   c8i[4][8];
  __shared__ int widxR[8], widxW[8];
  __shared__ float wvalR[8], wvalW[8];

  const int tid = threadIdx.x, lane = tid & 63, wave = tid >> 6;
  const int h = blockIdx.x & 3, b = blockIdx.x >> 2;
  float* memB = mem + ((size_t)((b<<2) + h))*NN*NHD;
  const float betaR = fminf(20.f, fmaxf(1.f, log1pf(__expf(betaRp[0]))));
  const float betaW = fminf(20.f, fmaxf(1.f, log1pf(__expf(betaWp[0]))));
  unsigned int* barB = bar + (b<<5);     // 128B region per batch
  unsigned gen = 0;

  // ---- init cached row norms (once) ----
  for (int n = tid; n < NN; n += 1024){
    const floatx4* rowp = (const floatx4*)(memB + (size_t)n*NHD);
    float ss = 0.f;
    #pragma unroll
    for (int q=0;q<16;q++){ floatx4 a = rowp[q]; ss += a[0]*a[0]+a[1]*a[1]+a[2]*a[2]+a[3]*a[3]; }
    rnorm[n] = rsqrtf(ss + 1e-8f);
  }

  const int oc = tid & 255, part = tid >> 8;
  const int c_out = ((oc>>6)<<8) + (h<<6) + (oc&63);   // column into IF for islice[oc]

  for (int t=0; t<NT; t++){
    // P1: load rv carry (full 256 of this batch)
    if (tid < 256) rv_s[tid] = rvs[((size_t)t*NB + b)*ND + tid];
    __syncthreads();
    // P2: i = iface_t + rv@W_if_r + b_if  — 4-way e-split, contiguous bf16x8 loads
    {
      const u16x8* wp = (const u16x8*)(WifrT + ((size_t)c_out<<8) + (part<<6));
      const float* rp = &rv_s[part<<6];
      float a0=0.f, a1=0.f;
      #pragma unroll
      for (int u=0;u<8;u++){
        u16x8 w8 = wp[u];
        a0 += rp[(u<<3)+0]*bf2f(w8[0]) + rp[(u<<3)+1]*bf2f(w8[1])
            + rp[(u<<3)+2]*bf2f(w8[2]) + rp[(u<<3)+3]*bf2f(w8[3]);
        a1 += rp[(u<<3)+4]*bf2f(w8[4]) + rp[(u<<3)+5]*bf2f(w8[5])
            + rp[(u<<3)+6]*bf2f(w8[6]) + rp[(u<<3)+7]*bf2f(w8[7]);
      }
      part_lds[part][oc] = a0 + a1;
      if (wave == 15){  // gr scalar (col 4*ND+h), lane handles 4 e's
        const unsigned short* wg = WifrT + ((size_t)(4*ND + h)<<8) + (lane<<2);
        float pg = rv_s[(lane<<2)+0]*bf2f(wg[0]) + rv_s[(lane<<2)+1]*bf2f(wg[1])
                 + rv_s[(lane<<2)+2]*bf2f(wg[2]) + rv_s[(lane<<2)+3]*bf2f(wg[3]);
        #pragma unroll
        for (int o=32;o;o>>=1) pg += __shfl_xor(pg,o);
        if (lane == 0)
          grraw_s = pg + iface[((size_t)(b*NT + t))*NIF + 4*ND + h] + b_if[4*ND + h];
      }
    }
    __syncthreads();
    if (tid < 256)
      islice[tid] = part_lds[0][tid] + part_lds[1][tid] + part_lds[2][tid] + part_lds[3][tid]
                  + iface[((size_t)(b*NT + t))*NIF + c_out] + b_if[c_out];
    __syncthreads();
    // P3: normalize keys, sigmoids
    if (wave == 0){
      float vv = islice[lane]; float ss = vv*vv;
      #pragma unroll
      for (int o=32;o;o>>=1) ss += __shfl_xor(ss,o);
      knr[lane] = vv * rsqrtf(ss + 1e-8f);
    } else if (wave == 1){
      float vv = islice[64+lane]; float ss = vv*vv;
      #pragma unroll
      for (int o=32;o;o>>=1) ss += __shfl_xor(ss,o);
      knw[lane] = vv * rsqrtf(ss + 1e-8f);
    } else if (wave == 2){
      es_s[lane] = 1.f/(1.f + __expf(-islice[192+lane]));
    } else if (wave == 3 && lane == 0){
      g_s = 1.f/(1.f + __expf(-grraw_s));
    }
    __syncthreads();
    // P4: stream 2048 rows, 2 rows/thread, cached norms
    {
      const floatx4* memv = (const floatx4*)memB;
      const int n0 = tid, n1 = tid + 1024;
      float dr0=0.f,dw0=0.f,dr1=0.f,dw1=0.f;
      #pragma unroll
      for (int q=0;q<16;q++){
        floatx4 kr4 = *(const floatx4*)(&knr[q<<2]);
        floatx4 kw4 = *(const floatx4*)(&knw[q<<2]);
        floatx4 a  = memv[((size_t)n0<<4) + q];
        floatx4 c2 = memv[((size_t)n1<<4) + q];
        dr0 += a[0]*kr4[0] + a[1]*kr4[1] + a[2]*kr4[2] + a[3]*kr4[3];
        dw0 += a[0]*kw4[0] + a[1]*kw4[1] + a[2]*kw4[2] + a[3]*kw4[3];
        dr1 += c2[0]*kr4[0] + c2[1]*kr4[1] + c2[2]*kr4[2] + c2[3]*kr4[3];
        dw1 += c2[0]*kw4[0] + c2[1]*kw4[1] + c2[2]*kw4[2] + c2[3]*kw4[3];
      }
      float r0 = rnorm[n0], r1 = rnorm[n1];
      simR[n0] = dr0*r0; simW[n0] = dw0*r0;
      simR[n1] = dr1*r1; simW[n1] = dw1*r1;
    }
    __syncthreads();
    // P5: top-8 — waves 0..3: (R-lo, W-lo, R-hi, W-hi), candidates in registers,
    //     tournament tree + wave butterfly, 8 sorted rounds
    if (wave < 4){
      const float* sims = (wave & 1) ? simW : simR;
      const int base = (wave >> 1) << 10;
      float cand[16];
      #pragma unroll
      for (int i=0;i<16;i++) cand[i] = sims[base + lane + (i<<6)];
      #pragma unroll
      for (int rr=0;rr<8;rr++){
        float v8[8]; int j8[8];
        #pragma unroll
        for (int i=0;i<8;i++){
          bool gsel = cand[2*i+1] > cand[2*i];
          v8[i] = gsel ? cand[2*i+1] : cand[2*i];
          j8[i] = gsel ? (2*i+1) : (2*i);
        }
        float v4[4]; int j4[4];
        #pragma unroll
        for (int i=0;i<4;i++){
          bool gsel = v8[2*i+1] > v8[2*i];
          v4[i] = gsel ? v8[2*i+1] : v8[2*i];
          j4[i] = gsel ? j8[2*i+1] : j8[2*i];
        }
        float v2[2]; int j2[2];
        #pragma unroll
        for (int i=0;i<2;i++){
          bool gsel = v4[2*i+1] > v4[2*i];
          v2[i] = gsel ? v4[2*i+1] : v4[2*i];
          j2[i] = gsel ? j4[2*i+1] : j4[2*i];
        }
        bool gsel = v2[1] > v2[0];
        float bv = gsel ? v2[1] : v2[0];
        int   bj = gsel ? j2[1] : j2[0];
        int bi = base + lane + (bj<<6);
        #pragma unroll
        for (int o=32;o;o>>=1){
          float ov = __shfl_xor(bv,o); int oi = __shfl_xor(bi,o);
          if (ov > bv || (ov == bv && oi < bi)){ bv = ov; bi = oi; }
        }
        if (lane == 0){ c8v[wave][rr] = bv; c8i[wave][rr] = bi; }
        if (lane == (bi & 63)){
          int wj = (bi >> 6) & 15;
          #pragma unroll
          for (int i=0;i<16;i++) if (i == wj) cand[i] = -1e38f;
        }
      }
    }
    __syncthreads();
    // merge two sorted top-8 halves (two-pointer) + softmax weights
    if (tid == 0 || tid == 64){
      int s2 = (tid == 0) ? 0 : 1;
      float beta = (tid == 0) ? betaR : betaW;
      const float* A  = c8v[s2];   const int* Ai  = c8i[s2];
      const float* Bv = c8v[s2+2]; const int* Bi2 = c8i[s2+2];
      int ia = 0, ib = 0;
      float mx = fmaxf(A[0], Bv[0]);
      float wsum = 0.f; float wv8[8]; int wi8[8];
      #pragma unroll
      for (int k2=0;k2<8;k2++){
        float va = A[ia], vb = Bv[ib];
        bool ta = (va > vb) || (va == vb && Ai[ia] < Bi2[ib]);
        float v = ta ? va : vb; int ix = ta ? Ai[ia] : Bi2[ib];
        if (ta) ia++; else ib++;
        float w = __expf(beta*(v - mx));
        wsum += w; wv8[k2] = w; wi8[k2] = ix;
      }
      float inv = 1.f/wsum;
      #pragma unroll
      for (int k2=0;k2<8;k2++){
        if (tid == 0){ widxR[k2] = wi8[k2]; wvalR[k2] = wv8[k2]*inv; }
        else         { widxW[k2] = wi8[k2]; wvalW[k2] = wv8[k2]*inv; }
      }
    }
    __syncthreads();
    // P6: rv_new gather from OLD mem (8 rows), write next carry
    if (wave == 0){
      float acc0 = 0.f;
      #pragma unroll
      for (int j=0;j<8;j++)
        acc0 += wvalR[j] * memB[(size_t)widxR[j]*NHD + lane];
      rvs[((size_t)(t+1)*NB + b)*ND + (h<<6) + lane] = acc0;
    }
    __syncthreads();
    // P7: sparse write update on 8 rows + fused norm-cache update (rows are wave-aligned)
    if (tid < 512){
      int jr = tid >> 6, d = tid & 63;
      int n = widxW[jr]; float w = wvalW[jr];
      size_t idx = (size_t)n*NHD + d;
      float mo = memB[idx];
      float nv = mo*(1.f - w*es_s[d]) + w*(g_s*islice[128+d]);
      memB[idx] = nv;
      float ss = nv*nv;
      #pragma unroll
      for (int o=32;o;o>>=1) ss += __shfl_xor(ss,o);
      if (d == 0) rnorm[n] = rsqrtf(ss + 1e-8f);
    }
    __syncthreads();
    // device-scope barrier across the 4 blocks of this batch
    if (tid == 0){
      __threadfence();
      unsigned arr = __hip_atomic_fetch_add(&barB[0], 1u, __ATOMIC_ACQ_REL, __HIP_MEMORY_SCOPE_AGENT);
      if (arr == 3u){
        __hip_atomic_store(&barB[0], 0u, __ATOMIC_RELAXED, __HIP_MEMORY_SCOPE_AGENT);
        __hip_atomic_fetch_add(&barB[16], 1u, __ATOMIC_RELEASE, __HIP_MEMORY_SCOPE_AGENT);
      } else {
        unsigned tgt = gen + 1;
        while ((int)(__hip_atomic_load(&barB[16], __ATOMIC_ACQUIRE, __HIP_MEMORY_SCOPE_AGENT) - tgt) < 0){
          __builtin_amdgcn_s_sleep(1);
        }
      }
      __threadfence();
      gen++;
    }
    __syncthreads();
  }
}

// build A = [hf_bf16 | rv_bf16] rows (b*256+t), K=768
__global__ __launch_bounds__(256)
void k_abig(const unsigned short* __restrict__ hb, const float* __restrict__ rvs,
            unsigned short* __restrict__ ab)
{
  int row = blockIdx.x; int b = row >> 8, t = row & 255;
  #pragma unroll
  for (int j=0;j<3;j++){
    int col = threadIdx.x + (j<<8);
    unsigned short v;
    if (col < NE) v = hb[(size_t)row*NE + col];
    else v = f2bf(rvs[((size_t)t*NB + b)*ND + (col-NE)]);
    ab[(size_t)row*768 + col] = v;
  }
}

extern "C" void kernel_launch(void* const* d_in, const int* in_sizes, int n_in,
                              void* d_out, int out_size, void* d_ws, size_t ws_size,
                              hipStream_t stream)
{
  (void)in_sizes; (void)n_in; (void)out_size; (void)ws_size;
  const int*   ids   = (const int*)  d_in[0];
  const float* emb   = (const float*)d_in[1];
  const float* pos   = (const float*)d_in[2];
  const float* ln1g  = (const float*)d_in[3];
  const float* ln1b  = (const float*)d_in[4];
  const float* ln2g  = (const float*)d_in[5];
  const float* ln2b  = (const float*)d_in[6];
  const float* Wq    = (const float*)d_in[7];
  const float* Wk    = (const float*)d_in[8];
  const float* Wv    = (const float*)d_in[9];
  const float* Wo    = (const float*)d_in[10];
  const float* W1    = (const float*)d_in[11];
  const float* b1    = (const float*)d_in[12];
  const float* W2    = (const float*)d_in[13];
  const float* b2    = (const float*)d_in[14];
  const float* lnfg  = (const float*)d_in[15];
  const float* lnfb  = (const float*)d_in[16];
  const float* Wifh  = (const float*)d_in[17];
  const float* WifrF = (const float*)d_in[18];
  const float* bif   = (const float*)d_in[19];
  const float* Wlgh  = (const float*)d_in[20];
  const float* Wlgr  = (const float*)d_in[21];
  const float* blg   = (const float*)d_in[22];
  const float* betaR = (const float*)d_in[23];
  const float* betaW = (const float*)d_in[24];
  const float* memi  = (const float*)d_in[25];
  float* out = (float*)d_out;
  char* ws = (char*)d_ws;

  size_t off = 0;
  auto alloc = [&](size_t bytes)->char*{
    char* p = ws + off;
    off = (off + bytes + 255) & ~(size_t)255;
    return p;
  };
  unsigned short* BTqkv = (unsigned short*)alloc((size_t)NL*1536*512*2);
  unsigned short* BTo   = (unsigned short*)alloc((size_t)NL*512*512*2);
  unsigned short* BT1   = (unsigned short*)alloc((size_t)NL*2048*512*2);
  unsigned short* BT2   = (unsigned short*)alloc((size_t)NL*512*2048*2);
  unsigned short* BTif  = (unsigned short*)alloc((size_t)1028*512*2);
  unsigned short* BTlm  = (unsigned short*)alloc((size_t)32000*768*2);
  unsigned short* Wifrb = (unsigned short*)alloc((size_t)1028*256*2);   // TRANSPOSED [c][e]
  float* xbuf  = (float*)alloc((size_t)NMT*NE*4);
  unsigned short* hb  = (unsigned short*)alloc((size_t)NMT*NE*2);
  float* qkvb  = (float*)alloc((size_t)NMT*1536*4);
  unsigned short* ob  = (unsigned short*)alloc((size_t)NMT*NE*2);
  unsigned short* f1b = (unsigned short*)alloc((size_t)NMT*NF*2);
  float* ifb   = (float*)alloc((size_t)NMT*NIF*4);
  float* rvs   = (float*)alloc((size_t)(NT+1)*NB*ND*4);
  float* memst = (float*)alloc((size_t)NB*NHM*NN*NHD*4);
  unsigned short* abig = (unsigned short*)alloc((size_t)NMT*768*2);
  unsigned int* bar = (unsigned int*)alloc(1024);

  // ---- weight prep (transpose + bf16) ----
  for (int l=0;l<NL;l++){
    k_tcvt<<<dim3(16,16),256,0,stream>>>(Wq + (size_t)l*NE*NE, NE, NE, BTqkv + (size_t)l*1536*512,            512);
    k_tcvt<<<dim3(16,16),256,0,stream>>>(Wk + (size_t)l*NE*NE, NE, NE, BTqkv + (size_t)l*1536*512 + 512*512,  512);
    k_tcvt<<<dim3(16,16),256,0,stream>>>(Wv + (size_t)l*NE*NE, NE, NE, BTqkv + (size_t)l*1536*512 + 2*512*512,512);
    k_tcvt<<<dim3(16,16),256,0,stream>>>(Wo + (size_t)l*NE*NE, NE, NE, BTo + (size_t)l*512*512, 512);
    k_tcvt<<<dim3(64,16),256,0,stream>>>(W1 + (size_t)l*NE*NF, NE, NF, BT1 + (size_t)l*2048*512, 512);
    k_tcvt<<<dim3(16,64),256,0,stream>>>(W2 + (size_t)l*NF*NE, NF, NE, BT2 + (size_t)l*512*2048, 2048);
  }
  k_tcvt<<<dim3(33,16),256,0,stream>>>(Wifh, NE, NIF, BTif, 512);
  k_tcvt<<<dim3(1000,16),256,0,stream>>>(Wlgh, NE, NV, BTlm, 768);
  k_tcvt<<<dim3(1000,8),256,0,stream>>>(Wlgr, ND, NV, BTlm + 512, 768);
  // transposed W_if_r for the scan: WifrT[c*256+e] = W_if_r[e][c]
  k_tcvt<<<dim3(33,8),256,0,stream>>>(WifrF, ND, NIF, Wifrb, ND);

  hipMemsetAsync(bar, 0, 1024, stream);
  hipMemsetAsync(rvs, 0, (size_t)NB*ND*4, stream);

  k_embed<<<dim3((NMT*NE)/256),256,0,stream>>>(ids, emb, pos, xbuf);
  k_initmem<<<dim3((NB*NHM*NN*NHD)/256),256,0,stream>>>(memi, memst);

  // ---- transformer ----
  for (int l=0;l<NL;l++){
    k_ln<<<dim3(NMT/4),256,0,stream>>>(xbuf, ln1g + l*NE, ln1b + l*NE, hb);
    k_gemm<<<dim3(16,12),256,0,stream>>>(hb, BTqkv + (size_t)l*1536*512, NMT, 1536, 512,
                                         qkvb, (unsigned short*)nullptr, (const float*)nullptr, (const float*)nullptr, 0);
    k_attn<<<dim3(NB*NHA*4),256,0,stream>>>(qkvb, ob);
    k_gemm<<<dim3(16,4),256,0,stream>>>(ob, BTo + (size_t)l*512*512, NMT, 512, 512,
                                        xbuf, (unsigned short*)nullptr, (const float*)nullptr, xbuf, 0);
    k_ln<<<dim3(NMT/4),256,0,stream>>>(xbuf, ln2g + l*NE, ln2b + l*NE, hb);
    k_gemm<<<dim3(16,16),256,0,stream>>>(hb, BT1 + (size_t)l*2048*512, NMT, 2048, 512,
                                         (float*)nullptr, f1b, b1 + l*NF, (const float*)nullptr, 1);
    k_gemm<<<dim3(16,4),256,0,stream>>>(f1b, BT2 + (size_t)l*512*2048, NMT, 512, 2048,
                                        xbuf, (unsigned short*)nullptr, b2 + l*NE, xbuf, 0);
  }
  k_ln<<<dim3(NMT/4),256,0,stream>>>(xbuf, lnfg, lnfb, hb);
  k_gemm<<<dim3(16,9),256,0,stream>>>(hb, BTif, NMT, NIF, 512,
                                      ifb, (unsigned short*)nullptr, (const float*)nullptr, (const float*)nullptr, 0);
  // ---- memory scan (single persistent kernel, 1024 threads/block) ----
  k_scan<<<dim3(NB*NHM),1024,0,stream>>>(ifb, Wifrb, bif, betaR, betaW, memst, rvs, bar);
  // ---- fused LM head: out = hf@W_lg_h + b_lg + rv@W_lg_r ----
  k_abig<<<dim3(NMT),256,0,stream>>>(hb, rvs, abig);
  k_gemm<<<dim3(16,250),256,0,stream>>>(abig, BTlm, NMT, NV, 768,
                                        out, (unsigned short*)nullptr, blg, (const float*)nullptr, 0);
}

// Round 2
// 8994.186 us; speedup vs baseline: 1.4806x; 1.0680x over previous
//
#include <hip/hip_runtime.h>
#include <cmath>

#define NB 8      // batch
#define NT 256    // seq len
#define NE 512    // embed
#define NF 2048   // ffn
#define NV 32000  // vocab
#define ND 256    // mem dim
#define NN 2048   // mem slots
#define NL 2
#define NHM 4     // mem heads
#define NHD 64
#define NHA 8     // attn heads
#define NIF 1028
#define NMT (NB*NT)

typedef __bf16 bf16x8 __attribute__((ext_vector_type(8)));
typedef float floatx4 __attribute__((ext_vector_type(4)));
typedef unsigned short u16x8 __attribute__((ext_vector_type(8)));

__device__ __forceinline__ unsigned short f2bf(float f){
  unsigned u = __float_as_uint(f);
  u += 0x7fffu + ((u>>16)&1u);
  return (unsigned short)(u>>16);
}
__device__ __forceinline__ float bf2f(unsigned short h){
  return __uint_as_float(((unsigned)h)<<16);
}

// ---- transpose+convert: out[n*ldo + k] = bf16(in[k*N + n]) ----
__global__ __launch_bounds__(256)
void k_tcvt(const float* __restrict__ in, int K, int N,
            unsigned short* __restrict__ out, int ldo)
{
  __shared__ float tile[32][33];
  int n0 = blockIdx.x<<5, k0 = blockIdx.y<<5;
  int tx = threadIdx.x & 31, ty = threadIdx.x >> 5;
  #pragma unroll
  for (int i=0;i<4;i++){
    int k = k0 + (ty<<2) + i, n = n0 + tx;
    tile[(ty<<2)+i][tx] = (k<K && n<N) ? in[(size_t)k*N + n] : 0.f;
  }
  __syncthreads();
  #pragma unroll
  for (int i=0;i<4;i++){
    int n = n0 + (ty<<2) + i, k = k0 + tx;
    if (n<N && k<K) out[(size_t)n*ldo + k] = f2bf(tile[tx][(ty<<2)+i]);
  }
}

__global__ void k_embed(const int* __restrict__ ids, const float* __restrict__ emb,
                        const float* __restrict__ pos, float* __restrict__ x)
{
  int i = blockIdx.x*blockDim.x + threadIdx.x;
  if (i >= NMT*NE) return;
  int e = i & (NE-1); int row = i >> 9; int t = row & (NT-1);
  x[i] = emb[(size_t)ids[row]*NE + e] + pos[t*NE + e];
}

__global__ void k_initmem(const float* __restrict__ mi, float* __restrict__ mem)
{
  int i = blockIdx.x*blockDim.x + threadIdx.x;
  if (i >= NB*NHM*NN*NHD) return;
  int d = i & 63; int n = (i>>6) & (NN-1); int h = (i>>17) & 3;
  mem[i] = mi[n*ND + h*64 + d];
}

// one wave per row of 512
__global__ __launch_bounds__(256)
void k_ln(const float* __restrict__ x, const float* __restrict__ g,
          const float* __restrict__ bb, unsigned short* __restrict__ out)
{
  int row = (blockIdx.x<<2) + (threadIdx.x>>6);
  int lane = threadIdx.x & 63;
  const float* xr = x + (size_t)row*NE;
  float v[8]; float s = 0.f;
  #pragma unroll
  for (int m=0;m<8;m++){ v[m] = xr[lane + (m<<6)]; s += v[m]; }
  #pragma unroll
  for (int o=32;o;o>>=1) s += __shfl_xor(s,o);
  float mean = s * (1.f/NE);
  float vs = 0.f;
  #pragma unroll
  for (int m=0;m<8;m++){ float d=v[m]-mean; vs += d*d; }
  #pragma unroll
  for (int o=32;o;o>>=1) vs += __shfl_xor(vs,o);
  float rstd = rsqrtf(vs*(1.f/NE) + 1e-5f);
  #pragma unroll
  for (int m=0;m<8;m++){
    int e = lane + (m<<6);
    out[(size_t)row*NE + e] = f2bf((v[m]-mean)*rstd*g[e] + bb[e]);
  }
}

// ---- GEMM: C[M,N] = A[M,K] @ BT[N,K]^T, bf16 in / fp32 acc, 128x128 tile ----
__global__ __launch_bounds__(256,2)
void k_gemm(const unsigned short* __restrict__ A, const unsigned short* __restrict__ BT,
            int M, int N, int K,
            float* __restrict__ Cf, unsigned short* __restrict__ Cb,
            const float* __restrict__ bias, const float* __restrict__ addsrc, int gelu)
{
  __shared__ __align__(16) unsigned short As[128*40];
  __shared__ __align__(16) unsigned short Bs[128*40];
  const int tid = threadIdx.x;
  const int lane = tid & 63, wave = tid >> 6;
  const int wm = wave >> 1, wn = wave & 1;
  const int l15 = lane & 15, qd = lane >> 4;
  const int rowA0 = blockIdx.x*128, rowB0 = blockIdx.y*128;

  floatx4 acc[4][4];
  #pragma unroll
  for (int i=0;i<4;i++)
    #pragma unroll
    for (int j=0;j<4;j++) acc[i][j] = 0.f;

  for (int k0=0; k0<K; k0+=32){
    #pragma unroll
    for (int it=0; it<2; it++){
      int c = tid + (it<<8);
      int r = c >> 2, c16 = c & 3;
      uint4 va = *(const uint4*)(A + (size_t)(rowA0+r)*K + k0 + (c16<<3));
      *(uint4*)(&As[r*40 + (c16<<3)]) = va;
      int rn = rowB0 + r; if (rn > N-1) rn = N-1;
      uint4 vb = *(const uint4*)(BT + (size_t)rn*K + k0 + (c16<<3));
      *(uint4*)(&Bs[r*40 + (c16<<3)]) = vb;
    }
    __syncthreads();
    bf16x8 af[4], bfv[4];
    #pragma unroll
    for (int i=0;i<4;i++)
      af[i] = *(const bf16x8*)(&As[(wm*64 + i*16 + l15)*40 + (qd<<3)]);
    #pragma unroll
    for (int j=0;j<4;j++)
      bfv[j] = *(const bf16x8*)(&Bs[(wn*64 + j*16 + l15)*40 + (qd<<3)]);
    #pragma unroll
    for (int i=0;i<4;i++)
      #pragma unroll
      for (int j=0;j<4;j++)
        acc[i][j] = __builtin_amdgcn_mfma_f32_16x16x32_bf16(af[i], bfv[j], acc[i][j], 0, 0, 0);
    __syncthreads();
  }
  #pragma unroll
  for (int i=0;i<4;i++){
    #pragma unroll
    for (int j=0;j<4;j++){
      int col = rowB0 + wn*64 + j*16 + l15;
      if (col < N){
        float bsv = bias ? bias[col] : 0.f;
        #pragma unroll
        for (int r4=0;r4<4;r4++){
          int row = rowA0 + wm*64 + i*16 + (qd<<2) + r4;
          float v = acc[i][j][r4] + bsv;
          if (gelu){
            float xx = v;
            v = 0.5f*xx*(1.f + tanhf(0.7978845608028654f*(xx + 0.044715f*xx*xx*xx)));
          }
          if (addsrc) v += addsrc[(size_t)row*N + col];
          if (Cf) Cf[(size_t)row*N + col] = v;
          if (Cb) Cb[(size_t)row*N + col] = f2bf(v);
        }
      }
    }
  }
}

// ---- causal attention, one block per (b, head, q-tile of 64); K/V bf16 in 64KB LDS ----
__global__ __launch_bounds__(256)
void k_attn(const float* __restrict__ qkv, unsigned short* __restrict__ ob)
{
  __shared__ unsigned short Ksh[256*64];   // XOR-swizzled columns
  __shared__ unsigned short Vsh[256*64];
  const int blk = blockIdx.x;
  const int qt = blk & 3, bh = blk >> 2;
  const int h = bh & 7, b = bh >> 3;
  const int lane = threadIdx.x & 63, wave = threadIdx.x >> 6;
  for (int tk = wave; tk < 256; tk += 4){
    size_t base = ((size_t)(b*NT + tk))*1536 + h*64 + lane;
    int sw = lane ^ ((tk<<1)&62);
    Ksh[tk*64 + sw]   = f2bf(qkv[base + 512]);
    Vsh[tk*64 + lane] = f2bf(qkv[base + 1024]);
  }
  __syncthreads();
  const int xm = (lane<<1)&62;
  for (int r=0;r<16;r++){
    int tq = qt*64 + wave*16 + r;
    float qreg = qkv[((size_t)(b*NT + tq))*1536 + h*64 + lane];
    int cmax = tq >> 6;
    float sarr[4] = {-1e30f,-1e30f,-1e30f,-1e30f};
    #pragma unroll
    for (int c=0;c<4;c++){
      if (c <= cmax){
        int tk = (c<<6) + lane;
        float a = 0.f;
        #pragma unroll 16
        for (int d=0; d<64; d++){
          float qd2 = __shfl(qreg, d);
          a += qd2 * bf2f(Ksh[tk*64 + (d ^ xm)]);
        }
        sarr[c] = (tk <= tq) ? a*0.125f : -1e30f;
      }
    }
    float m = fmaxf(fmaxf(sarr[0],sarr[1]), fmaxf(sarr[2],sarr[3]));
    #pragma unroll
    for (int o=32;o;o>>=1) m = fmaxf(m, __shfl_xor(m,o));
    float p[4]; float sum = 0.f;
    #pragma unroll
    for (int c=0;c<4;c++){ p[c] = (sarr[c] > -1e29f) ? __expf(sarr[c]-m) : 0.f; sum += p[c]; }
    #pragma unroll
    for (int o=32;o;o>>=1) sum += __shfl_xor(sum,o);
    float inv = 1.f/sum;
    #pragma unroll
    for (int c=0;c<4;c++) p[c] *= inv;
    float oacc = 0.f;
    #pragma unroll
    for (int c=0;c<4;c++){
      if (c <= cmax){
        int jmax = tq - (c<<6); if (jmax > 63) jmax = 63;
        for (int jj=0; jj<=jmax; jj++){
          float pj = __shfl(p[c], jj);
          oacc += pj * bf2f(Vsh[((c<<6)+jj)*64 + lane]);
        }
      }
    }
    ob[((size_t)(b*NT + tq))*NE + h*64 + lane] = f2bf(oacc);
  }
}

// ---- persistent memory-network scan: 32 blocks = (mem-head, batch), 1024 threads,
//      256 steps. NO device barrier / NO fences: the only cross-block data is rv
//      (4x64 floats per batch per step), exchanged via relaxed agent-scope atomics
//      (bypass L1/L2 -> coherence point) + per-(t,b) arrival flags. L2 stays warm.
//      Block mapping h=bid>>3, b=bid&7 puts a batch's 4 heads on one XCD.
// WifrT is TRANSPOSED: WifrT[c*256 + e] = W_if_r[e][c]  (bf16)
__global__ __launch_bounds__(1024)
void k_scan(const float* __restrict__ iface, const unsigned short* __restrict__ WifrT,
            const float* __restrict__ b_if, const float* __restrict__ betaRp,
            const float* __restrict__ betaWp, float* __restrict__ mem,
            float* __restrict__ rvs, unsigned int* __restrict__ flags)
{
  __shared__ float rv_s[ND];
  __shared__ float part_lds[4][256];
  __shared__ float islice[256];          // [g*64+d] g: 0=rk 1=wk 2=wv 3=er
  __shared__ float knr[64], knw[64], es_s[64];
  __shared__ float g_s, grraw_s;
  __shared__ float simR[NN], simW[NN];
  __shared__ float rnorm[NN];            // cached 1/||mem_row||
  __shared__ float c8v[4][8];            // per-wave sorted top-8 values
  __shared__ int   c8i[4][8];
  __shared__ int widxR[8], widxW[8];
  __shared__ float wvalR[8], wvalW[8];

  const int tid = threadIdx.x, lane = tid & 63, wave = tid >> 6;
  const int h = blockIdx.x >> 3, b = blockIdx.x & 7;   // heads of batch b share an XCD
  float* memB = mem + ((size_t)((b<<2) + h))*NN*NHD;
  const float betaR = fminf(20.f, fmaxf(1.f, log1pf(__expf(betaRp[0]))));
  const float betaW = fminf(20.f, fmaxf(1.f, log1pf(__expf(betaWp[0]))));

  // ---- init cached row norms (once) ----
  for (int n = tid; n < NN; n += 1024){
    const floatx4* rowp = (const floatx4*)(memB + (size_t)n*NHD);
    float ss = 0.f;
    #pragma unroll
    for (int q=0;q<16;q++){ floatx4 a = rowp[q]; ss += a[0]*a[0]+a[1]*a[1]+a[2]*a[2]+a[3]*a[3]; }
    rnorm[n] = rsqrtf(ss + 1e-8f);
  }

  const int oc = tid & 255, part = tid >> 8;
  const int c_out = ((oc>>6)<<8) + (h<<6) + (oc&63);   // column into IF for islice[oc]

  for (int t=0; t<NT; t++){
    // P0: wait for all 4 heads' rv[t] to be published (relaxed polls; no cache ops)
    if (t > 0 && tid == 0){
      while (__hip_atomic_load(&flags[(size_t)t*NB + b], __ATOMIC_RELAXED, __HIP_MEMORY_SCOPE_AGENT) < 4u)
        __builtin_amdgcn_s_sleep(1);
    }
    __syncthreads();
    // P1: load rv carry via coherent (L2-bypassing) loads
    if (tid < 256){
      const float* src = &rvs[((size_t)t*NB + b)*ND + tid];
      rv_s[tid] = (t == 0) ? *src
                : __hip_atomic_load(src, __ATOMIC_RELAXED, __HIP_MEMORY_SCOPE_AGENT);
    }
    __syncthreads();
    // P2: i = iface_t + rv@W_if_r + b_if  — 4-way e-split, contiguous bf16x8 loads
    {
      const u16x8* wp = (const u16x8*)(WifrT + ((size_t)c_out<<8) + (part<<6));
      const float* rp = &rv_s[part<<6];
      float a0=0.f, a1=0.f;
      #pragma unroll
      for (int u=0;u<8;u++){
        u16x8 w8 = wp[u];
        a0 += rp[(u<<3)+0]*bf2f(w8[0]) + rp[(u<<3)+1]*bf2f(w8[1])
            + rp[(u<<3)+2]*bf2f(w8[2]) + rp[(u<<3)+3]*bf2f(w8[3]);
        a1 += rp[(u<<3)+4]*bf2f(w8[4]) + rp[(u<<3)+5]*bf2f(w8[5])
            + rp[(u<<3)+6]*bf2f(w8[6]) + rp[(u<<3)+7]*bf2f(w8[7]);
      }
      part_lds[part][oc] = a0 + a1;
      if (wave == 15){  // gr scalar (col 4*ND+h), lane handles 4 e's
        const unsigned short* wg = WifrT + ((size_t)(4*ND + h)<<8) + (lane<<2);
        float pg = rv_s[(lane<<2)+0]*bf2f(wg[0]) + rv_s[(lane<<2)+1]*bf2f(wg[1])
                 + rv_s[(lane<<2)+2]*bf2f(wg[2]) + rv_s[(lane<<2)+3]*bf2f(wg[3]);
        #pragma unroll
        for (int o=32;o;o>>=1) pg += __shfl_xor(pg,o);
        if (lane == 0)
          grraw_s = pg + iface[((size_t)(b*NT + t))*NIF + 4*ND + h] + b_if[4*ND + h];
      }
    }
    __syncthreads();
    if (tid < 256)
      islice[tid] = part_lds[0][tid] + part_lds[1][tid] + part_lds[2][tid] + part_lds[3][tid]
                  + iface[((size_t)(b*NT + t))*NIF + c_out] + b_if[c_out];
    __syncthreads();
    // P3: normalize keys, sigmoids
    if (wave == 0){
      float vv = islice[lane]; float ss = vv*vv;
      #pragma unroll
      for (int o=32;o;o>>=1) ss += __shfl_xor(ss,o);
      knr[lane] = vv * rsqrtf(ss + 1e-8f);
    } else if (wave == 1){
      float vv = islice[64+lane]; float ss = vv*vv;
      #pragma unroll
      for (int o=32;o;o>>=1) ss += __shfl_xor(ss,o);
      knw[lane] = vv * rsqrtf(ss + 1e-8f);
    } else if (wave == 2){
      es_s[lane] = 1.f/(1.f + __expf(-islice[192+lane]));
    } else if (wave == 3 && lane == 0){
      g_s = 1.f/(1.f + __expf(-grraw_s));
    }
    __syncthreads();
    // P4: stream 2048 rows, 2 rows/thread, cached norms
    {
      const floatx4* memv = (const floatx4*)memB;
      const int n0 = tid, n1 = tid + 1024;
      float dr0=0.f,dw0=0.f,dr1=0.f,dw1=0.f;
      #pragma unroll
      for (int q=0;q<16;q++){
        floatx4 kr4 = *(const floatx4*)(&knr[q<<2]);
        floatx4 kw4 = *(const floatx4*)(&knw[q<<2]);
        floatx4 a  = memv[((size_t)n0<<4) + q];
        floatx4 c2 = memv[((size_t)n1<<4) + q];
        dr0 += a[0]*kr4[0] + a[1]*kr4[1] + a[2]*kr4[2] + a[3]*kr4[3];
        dw0 += a[0]*kw4[0] + a[1]*kw4[1] + a[2]*kw4[2] + a[3]*kw4[3];
        dr1 += c2[0]*kr4[0] + c2[1]*kr4[1] + c2[2]*kr4[2] + c2[3]*kr4[3];
        dw1 += c2[0]*kw4[0] + c2[1]*kw4[1] + c2[2]*kw4[2] + c2[3]*kw4[3];
      }
      float r0 = rnorm[n0], r1 = rnorm[n1];
      simR[n0] = dr0*r0; simW[n0] = dw0*r0;
      simR[n1] = dr1*r1; simW[n1] = dw1*r1;
    }
    __syncthreads();
    // P5: top-8 — waves 0..3: (R-lo, W-lo, R-hi, W-hi), candidates in registers,
    //     tournament tree + wave butterfly, 8 sorted rounds
    if (wave < 4){
      const float* sims = (wave & 1) ? simW : simR;
      const int base = (wave >> 1) << 10;
      float cand[16];
      #pragma unroll
      for (int i=0;i<16;i++) cand[i] = sims[base + lane + (i<<6)];
      #pragma unroll
      for (int rr=0;rr<8;rr++){
        float v8[8]; int j8[8];
        #pragma unroll
        for (int i=0;i<8;i++){
          bool gsel = cand[2*i+1] > cand[2*i];
          v8[i] = gsel ? cand[2*i+1] : cand[2*i];
          j8[i] = gsel ? (2*i+1) : (2*i);
        }
        float v4[4]; int j4[4];
        #pragma unroll
        for (int i=0;i<4;i++){
          bool gsel = v8[2*i+1] > v8[2*i];
          v4[i] = gsel ? v8[2*i+1] : v8[2*i];
          j4[i] = gsel ? j8[2*i+1] : j8[2*i];
        }
        float v2[2]; int j2[2];
        #pragma unroll
        for (int i=0;i<2;i++){
          bool gsel = v4[2*i+1] > v4[2*i];
          v2[i] = gsel ? v4[2*i+1] : v4[2*i];
          j2[i] = gsel ? j4[2*i+1] : j4[2*i];
        }
        bool gsel = v2[1] > v2[0];
        float bv = gsel ? v2[1] : v2[0];
        int   bj = gsel ? j2[1] : j2[0];
        int bi = base + lane + (bj<<6);
        #pragma unroll
        for (int o=32;o;o>>=1){
          float ov = __shfl_xor(bv,o); int oi = __shfl_xor(bi,o);
          if (ov > bv || (ov == bv && oi < bi)){ bv = ov; bi = oi; }
        }
        if (lane == 0){ c8v[wave][rr] = bv; c8i[wave][rr] = bi; }
        if (lane == (bi & 63)){
          int wj = (bi >> 6) & 15;
          #pragma unroll
          for (int i=0;i<16;i++) if (i == wj) cand[i] = -1e38f;
        }
      }
    }
    __syncthreads();
    // merge two sorted top-8 halves (two-pointer) + softmax weights
    if (tid == 0 || tid == 64){
      int s2 = (tid == 0) ? 0 : 1;
      float beta = (tid == 0) ? betaR : betaW;
      const float* A  = c8v[s2];   const int* Ai  = c8i[s2];
      const float* Bv = c8v[s2+2]; const int* Bi2 = c8i[s2+2];
      int ia = 0, ib = 0;
      float mx = fmaxf(A[0], Bv[0]);
      float wsum = 0.f; float wv8[8]; int wi8[8];
      #pragma unroll
      for (int k2=0;k2<8;k2++){
        float va = A[ia], vb = Bv[ib];
        bool ta = (va > vb) || (va == vb && Ai[ia] < Bi2[ib]);
        float v = ta ? va : vb; int ix = ta ? Ai[ia] : Bi2[ib];
        if (ta) ia++; else ib++;
        float w = __expf(beta*(v - mx));
        wsum += w; wv8[k2] = w; wi8[k2] = ix;
      }
      float inv = 1.f/wsum;
      #pragma unroll
      for (int k2=0;k2<8;k2++){
        if (tid == 0){ widxR[k2] = wi8[k2]; wvalR[k2] = wv8[k2]*inv; }
        else         { widxW[k2] = wi8[k2]; wvalW[k2] = wv8[k2]*inv; }
      }
    }
    __syncthreads();
    // P6: rv_new gather from OLD mem (8 rows); publish via coherent atomic stores
    if (wave == 0){
      float acc0 = 0.f;
      #pragma unroll
      for (int j=0;j<8;j++)
        acc0 += wvalR[j] * memB[(size_t)widxR[j]*NHD + lane];
      __hip_atomic_store(&rvs[((size_t)(t+1)*NB + b)*ND + (h<<6) + lane], acc0,
                         __ATOMIC_RELAXED, __HIP_MEMORY_SCOPE_AGENT);
    }
    __syncthreads();
    // P7: sparse write update on 8 rows + fused norm-cache update (rows are wave-aligned)
    if (tid < 512){
      int jr = tid >> 6, d = tid & 63;
      int n = widxW[jr]; float w = wvalW[jr];
      size_t idx = (size_t)n*NHD + d;
      float mo = memB[idx];
      float nv = mo*(1.f - w*es_s[d]) + w*(g_s*islice[128+d]);
      memB[idx] = nv;
      float ss = nv*nv;
      #pragma unroll
      for (int o=32;o;o>>=1) ss += __shfl_xor(ss,o);
      if (d == 0) rnorm[n] = rsqrtf(ss + 1e-8f);
    }
    __syncthreads();
    // P8: signal rv[t+1] ready. tid 0 is lane 0 of wave 0: its vmcnt covers the
    // wave-wide atomic stores of P6 (already at coherence point -> no cache ops).
    if (tid == 0){
      asm volatile("s_waitcnt vmcnt(0)" ::: "memory");
      __hip_atomic_fetch_add(&flags[(size_t)(t+1)*NB + b], 1u,
                             __ATOMIC_RELAXED, __HIP_MEMORY_SCOPE_AGENT);
    }
    // no further sync needed: next-iteration poll (tid 0) includes own arrival,
    // and __syncthreads after the poll orders the rest of the block.
  }
}

// build A = [hf_bf16 | rv_bf16] rows (b*256+t), K=768
__global__ __launch_bounds__(256)
void k_abig(const unsigned short* __restrict__ hb, const float* __restrict__ rvs,
            unsigned short* __restrict__ ab)
{
  int row = blockIdx.x; int b = row >> 8, t = row & 255;
  #pragma unroll
  for (int j=0;j<3;j++){
    int col = threadIdx.x + (j<<8);
    unsigned short v;
    if (col < NE) v = hb[(size_t)row*NE + col];
    else v = f2bf(rvs[((size_t)t*NB + b)*ND + (col-NE)]);
    ab[(size_t)row*768 + col] = v;
  }
}

extern "C" void kernel_launch(void* const* d_in, const int* in_sizes, int n_in,
                              void* d_out, int out_size, void* d_ws, size_t ws_size,
                              hipStream_t stream)
{
  (void)in_sizes; (void)n_in; (void)out_size; (void)ws_size;
  const int*   ids   = (const int*)  d_in[0];
  const float* emb   = (const float*)d_in[1];
  const float* pos   = (const float*)d_in[2];
  const float* ln1g  = (const float*)d_in[3];
  const float* ln1b  = (const float*)d_in[4];
  const float* ln2g  = (const float*)d_in[5];
  const float* ln2b  = (const float*)d_in[6];
  const float* Wq    = (const float*)d_in[7];
  const float* Wk    = (const float*)d_in[8];
  const float* Wv    = (const float*)d_in[9];
  const float* Wo    = (const float*)d_in[10];
  const float* W1    = (const float*)d_in[11];
  const float* b1    = (const float*)d_in[12];
  const float* W2    = (const float*)d_in[13];
  const float* b2    = (const float*)d_in[14];
  const float* lnfg  = (const float*)d_in[15];
  const float* lnfb  = (const float*)d_in[16];
  const float* Wifh  = (const float*)d_in[17];
  const float* WifrF = (const float*)d_in[18];
  const float* bif   = (const float*)d_in[19];
  const float* Wlgh  = (const float*)d_in[20];
  const float* Wlgr  = (const float*)d_in[21];
  const float* blg   = (const float*)d_in[22];
  const float* betaR = (const float*)d_in[23];
  const float* betaW = (const float*)d_in[24];
  const float* memi  = (const float*)d_in[25];
  float* out = (float*)d_out;
  char* ws = (char*)d_ws;

  size_t off = 0;
  auto alloc = [&](size_t bytes)->char*{
    char* p = ws + off;
    off = (off + bytes + 255) & ~(size_t)255;
    return p;
  };
  unsigned short* BTqkv = (unsigned short*)alloc((size_t)NL*1536*512*2);
  unsigned short* BTo   = (unsigned short*)alloc((size_t)NL*512*512*2);
  unsigned short* BT1   = (unsigned short*)alloc((size_t)NL*2048*512*2);
  unsigned short* BT2   = (unsigned short*)alloc((size_t)NL*512*2048*2);
  unsigned short* BTif  = (unsigned short*)alloc((size_t)1028*512*2);
  unsigned short* BTlm  = (unsigned short*)alloc((size_t)32000*768*2);
  unsigned short* Wifrb = (unsigned short*)alloc((size_t)1028*256*2);   // TRANSPOSED [c][e]
  float* xbuf  = (float*)alloc((size_t)NMT*NE*4);
  unsigned short* hb  = (unsigned short*)alloc((size_t)NMT*NE*2);
  float* qkvb  = (float*)alloc((size_t)NMT*1536*4);
  unsigned short* ob  = (unsigned short*)alloc((size_t)NMT*NE*2);
  unsigned short* f1b = (unsigned short*)alloc((size_t)NMT*NF*2);
  float* ifb   = (float*)alloc((size_t)NMT*NIF*4);
  float* rvs   = (float*)alloc((size_t)(NT+1)*NB*ND*4);
  float* memst = (float*)alloc((size_t)NB*NHM*NN*NHD*4);
  unsigned short* abig = (unsigned short*)alloc((size_t)NMT*768*2);
  unsigned int* flags = (unsigned int*)alloc(16384);   // (NT+1)*NB arrival counters

  // ---- weight prep (transpose + bf16) ----
  for (int l=0;l<NL;l++){
    k_tcvt<<<dim3(16,16),256,0,stream>>>(Wq + (size_t)l*NE*NE, NE, NE, BTqkv + (size_t)l*1536*512,            512);
    k_tcvt<<<dim3(16,16),256,0,stream>>>(Wk + (size_t)l*NE*NE, NE, NE, BTqkv + (size_t)l*1536*512 + 512*512,  512);
    k_tcvt<<<dim3(16,16),256,0,stream>>>(Wv + (size_t)l*NE*NE, NE, NE, BTqkv + (size_t)l*1536*512 + 2*512*512,512);
    k_tcvt<<<dim3(16,16),256,0,stream>>>(Wo + (size_t)l*NE*NE, NE, NE, BTo + (size_t)l*512*512, 512);
    k_tcvt<<<dim3(64,16),256,0,stream>>>(W1 + (size_t)l*NE*NF, NE, NF, BT1 + (size_t)l*2048*512, 512);
    k_tcvt<<<dim3(16,64),256,0,stream>>>(W2 + (size_t)l*NF*NE, NF, NE, BT2 + (size_t)l*512*2048, 2048);
  }
  k_tcvt<<<dim3(33,16),256,0,stream>>>(Wifh, NE, NIF, BTif, 512);
  k_tcvt<<<dim3(1000,16),256,0,stream>>>(Wlgh, NE, NV, BTlm, 768);
  k_tcvt<<<dim3(1000,8),256,0,stream>>>(Wlgr, ND, NV, BTlm + 512, 768);
  // transposed W_if_r for the scan: WifrT[c*256+e] = W_if_r[e][c]
  k_tcvt<<<dim3(33,8),256,0,stream>>>(WifrF, ND, NIF, Wifrb, ND);

  hipMemsetAsync(flags, 0, 16384, stream);
  hipMemsetAsync(rvs, 0, (size_t)NB*ND*4, stream);

  k_embed<<<dim3((NMT*NE)/256),256,0,stream>>>(ids, emb, pos, xbuf);
  k_initmem<<<dim3((NB*NHM*NN*NHD)/256),256,0,stream>>>(memi, memst);

  // ---- transformer ----
  for (int l=0;l<NL;l++){
    k_ln<<<dim3(NMT/4),256,0,stream>>>(xbuf, ln1g + l*NE, ln1b + l*NE, hb);
    k_gemm<<<dim3(16,12),256,0,stream>>>(hb, BTqkv + (size_t)l*1536*512, NMT, 1536, 512,
                                         qkvb, (unsigned short*)nullptr, (const float*)nullptr, (const float*)nullptr, 0);
    k_attn<<<dim3(NB*NHA*4),256,0,stream>>>(qkvb, ob);
    k_gemm<<<dim3(16,4),256,0,stream>>>(ob, BTo + (size_t)l*512*512, NMT, 512, 512,
                                        xbuf, (unsigned short*)nullptr, (const float*)nullptr, xbuf, 0);
    k_ln<<<dim3(NMT/4),256,0,stream>>>(xbuf, ln2g + l*NE, ln2b + l*NE, hb);
    k_gemm<<<dim3(16,16),256,0,stream>>>(hb, BT1 + (size_t)l*2048*512, NMT, 2048, 512,
                                         (float*)nullptr, f1b, b1 + l*NF, (const float*)nullptr, 1);
    k_gemm<<<dim3(16,4),256,0,stream>>>(f1b, BT2 + (size_t)l*512*2048, NMT, 512, 2048,
                                        xbuf, (unsigned short*)nullptr, b2 + l*NE, xbuf, 0);
  }
  k_ln<<<dim3(NMT/4),256,0,stream>>>(xbuf, lnfg, lnfb, hb);
  k_gemm<<<dim3(16,9),256,0,stream>>>(hb, BTif, NMT, NIF, 512,
                                      ifb, (unsigned short*)nullptr, (const float*)nullptr, (const float*)nullptr, 0);
  // ---- memory scan (single persistent kernel, 1024 threads/block, fence-free) ----
  k_scan<<<dim3(NB*NHM),1024,0,stream>>>(ifb, Wifrb, bif, betaR, betaW, memst, rvs, flags);
  // ---- fused LM head: out = hf@W_lg_h + b_lg + rv@W_lg_r ----
  k_abig<<<dim3(NMT),256,0,stream>>>(hb, rvs, abig);
  k_gemm<<<dim3(16,250),256,0,stream>>>(abig, BTlm, NMT, NV, 768,
                                        out, (unsigned short*)nullptr, blg, (const float*)nullptr, 0);
}

// Round 3
// 7012.186 us; speedup vs baseline: 1.8990x; 1.2827x over previous
//
#include <hip/hip_runtime.h>
#include <cmath>

#define NB 8      // batch
#define NT 256    // seq len
#define NE 512    // embed
#define NF 2048   // ffn
#define NV 32000  // vocab
#define ND 256    // mem dim
#define NN 2048   // mem slots
#define NL 2
#define NHM 4     // mem heads
#define NHD 64
#define NHA 8     // attn heads
#define NIF 1028
#define NMT (NB*NT)

typedef __bf16 bf16x8 __attribute__((ext_vector_type(8)));
typedef float floatx4 __attribute__((ext_vector_type(4)));
typedef float floatx2 __attribute__((ext_vector_type(2)));

__device__ __forceinline__ unsigned short f2bf(float f){
  unsigned u = __float_as_uint(f);
  u += 0x7fffu + ((u>>16)&1u);
  return (unsigned short)(u>>16);
}
__device__ __forceinline__ float bf2f(unsigned short h){
  return __uint_as_float(((unsigned)h)<<16);
}

// ---- transpose+convert: out[n*ldo + k] = bf16(in[k*N + n]) ----
__global__ __launch_bounds__(256)
void k_tcvt(const float* __restrict__ in, int K, int N,
            unsigned short* __restrict__ out, int ldo)
{
  __shared__ float tile[32][33];
  int n0 = blockIdx.x<<5, k0 = blockIdx.y<<5;
  int tx = threadIdx.x & 31, ty = threadIdx.x >> 5;
  #pragma unroll
  for (int i=0;i<4;i++){
    int k = k0 + (ty<<2) + i, n = n0 + tx;
    tile[(ty<<2)+i][tx] = (k<K && n<N) ? in[(size_t)k*N + n] : 0.f;
  }
  __syncthreads();
  #pragma unroll
  for (int i=0;i<4;i++){
    int n = n0 + (ty<<2) + i, k = k0 + tx;
    if (n<N && k<K) out[(size_t)n*ldo + k] = f2bf(tile[tx][(ty<<2)+i]);
  }
}

__global__ void k_cvt(const float* __restrict__ in, unsigned short* __restrict__ out, int n)
{
  int i = blockIdx.x*blockDim.x + threadIdx.x;
  if (i<n) out[i] = f2bf(in[i]);
}

__global__ void k_embed(const int* __restrict__ ids, const float* __restrict__ emb,
                        const float* __restrict__ pos, float* __restrict__ x)
{
  int i = blockIdx.x*blockDim.x + threadIdx.x;
  if (i >= NMT*NE) return;
  int e = i & (NE-1); int row = i >> 9; int t = row & (NT-1);
  x[i] = emb[(size_t)ids[row]*NE + e] + pos[t*NE + e];
}

// writes BOTH layouts: mem row-major [bh][n][d], memC col-major [bh][d][n]
__global__ void k_initmem(const float* __restrict__ mi, float* __restrict__ mem,
                          float* __restrict__ memC)
{
  int i = blockIdx.x*blockDim.x + threadIdx.x;
  const int half = NB*NHM*NN*NHD;
  if (i < half){
    int d = i & 63; int n = (i>>6) & (NN-1); int h = (i>>17) & 3;
    mem[i] = mi[n*ND + h*64 + d];
  } else {
    i -= half;
    int n = i & (NN-1); int d = (i>>11) & 63; int h = (i>>17) & 3;
    memC[i] = mi[n*ND + h*64 + d];
  }
}

// one wave per row of 512
__global__ __launch_bounds__(256)
void k_ln(const float* __restrict__ x, const float* __restrict__ g,
          const float* __restrict__ bb, unsigned short* __restrict__ out)
{
  int row = (blockIdx.x<<2) + (threadIdx.x>>6);
  int lane = threadIdx.x & 63;
  const float* xr = x + (size_t)row*NE;
  float v[8]; float s = 0.f;
  #pragma unroll
  for (int m=0;m<8;m++){ v[m] = xr[lane + (m<<6)]; s += v[m]; }
  #pragma unroll
  for (int o=32;o;o>>=1) s += __shfl_xor(s,o);
  float mean = s * (1.f/NE);
  float vs = 0.f;
  #pragma unroll
  for (int m=0;m<8;m++){ float d=v[m]-mean; vs += d*d; }
  #pragma unroll
  for (int o=32;o;o>>=1) vs += __shfl_xor(vs,o);
  float rstd = rsqrtf(vs*(1.f/NE) + 1e-5f);
  #pragma unroll
  for (int m=0;m<8;m++){
    int e = lane + (m<<6);
    out[(size_t)row*NE + e] = f2bf((v[m]-mean)*rstd*g[e] + bb[e]);
  }
}

// ---- GEMM: C[M,N] = A[M,K] @ BT[N,K]^T, bf16 in / fp32 acc, 128x128 tile ----
__global__ __launch_bounds__(256,2)
void k_gemm(const unsigned short* __restrict__ A, const unsigned short* __restrict__ BT,
            int M, int N, int K,
            float* __restrict__ Cf, unsigned short* __restrict__ Cb,
            const float* __restrict__ bias, const float* __restrict__ addsrc, int gelu)
{
  __shared__ __align__(16) unsigned short As[128*40];
  __shared__ __align__(16) unsigned short Bs[128*40];
  const int tid = threadIdx.x;
  const int lane = tid & 63, wave = tid >> 6;
  const int wm = wave >> 1, wn = wave & 1;
  const int l15 = lane & 15, qd = lane >> 4;
  const int rowA0 = blockIdx.x*128, rowB0 = blockIdx.y*128;

  floatx4 acc[4][4];
  #pragma unroll
  for (int i=0;i<4;i++)
    #pragma unroll
    for (int j=0;j<4;j++) acc[i][j] = 0.f;

  for (int k0=0; k0<K; k0+=32){
    #pragma unroll
    for (int it=0; it<2; it++){
      int c = tid + (it<<8);
      int r = c >> 2, c16 = c & 3;
      uint4 va = *(const uint4*)(A + (size_t)(rowA0+r)*K + k0 + (c16<<3));
      *(uint4*)(&As[r*40 + (c16<<3)]) = va;
      int rn = rowB0 + r; if (rn > N-1) rn = N-1;
      uint4 vb = *(const uint4*)(BT + (size_t)rn*K + k0 + (c16<<3));
      *(uint4*)(&Bs[r*40 + (c16<<3)]) = vb;
    }
    __syncthreads();
    bf16x8 af[4], bfv[4];
    #pragma unroll
    for (int i=0;i<4;i++)
      af[i] = *(const bf16x8*)(&As[(wm*64 + i*16 + l15)*40 + (qd<<3)]);
    #pragma unroll
    for (int j=0;j<4;j++)
      bfv[j] = *(const bf16x8*)(&Bs[(wn*64 + j*16 + l15)*40 + (qd<<3)]);
    #pragma unroll
    for (int i=0;i<4;i++)
      #pragma unroll
      for (int j=0;j<4;j++)
        acc[i][j] = __builtin_amdgcn_mfma_f32_16x16x32_bf16(af[i], bfv[j], acc[i][j], 0, 0, 0);
    __syncthreads();
  }
  #pragma unroll
  for (int i=0;i<4;i++){
    #pragma unroll
    for (int j=0;j<4;j++){
      int col = rowB0 + wn*64 + j*16 + l15;
      if (col < N){
        float bsv = bias ? bias[col] : 0.f;
        #pragma unroll
        for (int r4=0;r4<4;r4++){
          int row = rowA0 + wm*64 + i*16 + (qd<<2) + r4;
          float v = acc[i][j][r4] + bsv;
          if (gelu){
            float xx = v;
            v = 0.5f*xx*(1.f + tanhf(0.7978845608028654f*(xx + 0.044715f*xx*xx*xx)));
          }
          if (addsrc) v += addsrc[(size_t)row*N + col];
          if (Cf) Cf[(size_t)row*N + col] = v;
          if (Cb) Cb[(size_t)row*N + col] = f2bf(v);
        }
      }
    }
  }
}

// ---- causal attention, one block per (b, head, q-tile of 64); K/V bf16 in 64KB LDS ----
__global__ __launch_bounds__(256)
void k_attn(const float* __restrict__ qkv, unsigned short* __restrict__ ob)
{
  __shared__ unsigned short Ksh[256*64];   // XOR-swizzled columns
  __shared__ unsigned short Vsh[256*64];
  const int blk = blockIdx.x;
  const int qt = blk & 3, bh = blk >> 2;
  const int h = bh & 7, b = bh >> 3;
  const int lane = threadIdx.x & 63, wave = threadIdx.x >> 6;
  for (int tk = wave; tk < 256; tk += 4){
    size_t base = ((size_t)(b*NT + tk))*1536 + h*64 + lane;
    int sw = lane ^ ((tk<<1)&62);
    Ksh[tk*64 + sw]   = f2bf(qkv[base + 512]);
    Vsh[tk*64 + lane] = f2bf(qkv[base + 1024]);
  }
  __syncthreads();
  const int xm = (lane<<1)&62;
  for (int r=0;r<16;r++){
    int tq = qt*64 + wave*16 + r;
    float qreg = qkv[((size_t)(b*NT + tq))*1536 + h*64 + lane];
    int cmax = tq >> 6;
    float sarr[4] = {-1e30f,-1e30f,-1e30f,-1e30f};
    #pragma unroll
    for (int c=0;c<4;c++){
      if (c <= cmax){
        int tk = (c<<6) + lane;
        float a = 0.f;
        #pragma unroll 16
        for (int d=0; d<64; d++){
          float qd2 = __shfl(qreg, d);
          a += qd2 * bf2f(Ksh[tk*64 + (d ^ xm)]);
        }
        sarr[c] = (tk <= tq) ? a*0.125f : -1e30f;
      }
    }
    float m = fmaxf(fmaxf(sarr[0],sarr[1]), fmaxf(sarr[2],sarr[3]));
    #pragma unroll
    for (int o=32;o;o>>=1) m = fmaxf(m, __shfl_xor(m,o));
    float p[4]; float sum = 0.f;
    #pragma unroll
    for (int c=0;c<4;c++){ p[c] = (sarr[c] > -1e29f) ? __expf(sarr[c]-m) : 0.f; sum += p[c]; }
    #pragma unroll
    for (int o=32;o;o>>=1) sum += __shfl_xor(sum,o);
    float inv = 1.f/sum;
    #pragma unroll
    for (int c=0;c<4;c++) p[c] *= inv;
    float oacc = 0.f;
    #pragma unroll
    for (int c=0;c<4;c++){
      if (c <= cmax){
        int jmax = tq - (c<<6); if (jmax > 63) jmax = 63;
        for (int jj=0; jj<=jmax; jj++){
          float pj = __shfl(p[c], jj);
          oacc += pj * bf2f(Vsh[((c<<6)+jj)*64 + lane]);
        }
      }
    }
    ob[((size_t)(b*NT + tq))*NE + h*64 + lane] = f2bf(oacc);
  }
}

// ---- persistent memory-network scan: 32 blocks = (mem-head, batch), 1024 threads,
//      256 steps, fence-free rv exchange (per-batch flags). All global loads in the
//      hot loop are lane-coalesced: Wifr row-major (lanes span columns), memC is a
//      column-major [d][n] copy of mem so the 2048-row sim stream is lane-adjacent.
__global__ __launch_bounds__(1024)
void k_scan(const float* __restrict__ iface, const unsigned short* __restrict__ Wifrb,
            const float* __restrict__ b_if, const float* __restrict__ betaRp,
            const float* __restrict__ betaWp, float* __restrict__ mem,
            float* __restrict__ memC,
            float* __restrict__ rvs, unsigned int* __restrict__ flags)
{
  __shared__ float rv_s[ND];
  __shared__ float part_lds[4][256];
  __shared__ float islice[256];          // [g*64+d] g: 0=rk 1=wk 2=wv 3=er
  __shared__ float knrw[128];            // interleaved {knr[d], knw[d]}
  __shared__ float es_s[64];
  __shared__ float g_s, grraw_s;
  __shared__ float simR[NN], simW[NN];
  __shared__ float rnorm[NN];            // cached 1/||mem_row||
  __shared__ float c8v[4][8];            // per-wave sorted top-8 values
  __shared__ int   c8i[4][8];
  __shared__ int widxR[8], widxW[8];
  __shared__ float wvalR[8], wvalW[8];

  const int tid = threadIdx.x, lane = tid & 63, wave = tid >> 6;
  const int h = blockIdx.x >> 3, b = blockIdx.x & 7;   // heads of batch b share an XCD
  float* memB  = mem  + ((size_t)((b<<2) + h))*NN*NHD;
  float* memCB = memC + ((size_t)((b<<2) + h))*NN*NHD;
  const float betaR = fminf(20.f, fmaxf(1.f, log1pf(__expf(betaRp[0]))));
  const float betaW = fminf(20.f, fmaxf(1.f, log1pf(__expf(betaWp[0]))));

  // ---- init cached row norms (once), coalesced via memC ----
  for (int n = tid; n < NN; n += 1024){
    float ss = 0.f;
    #pragma unroll 8
    for (int d=0; d<64; d++){
      float v = memCB[(size_t)(d<<11) + n];
      ss += v*v;
    }
    rnorm[n] = rsqrtf(ss + 1e-8f);
  }

  const int oc = tid & 255, part = tid >> 8;
  const int c_out = ((oc>>6)<<8) + (h<<6) + (oc&63);   // column into IF for islice[oc]

  for (int t=0; t<NT; t++){
    // P0: wait for all 4 heads' rv[t] to be published (relaxed polls; no cache ops)
    if (t > 0 && tid == 0){
      while (__hip_atomic_load(&flags[(size_t)t*NB + b], __ATOMIC_RELAXED, __HIP_MEMORY_SCOPE_AGENT) < 4u)
        __builtin_amdgcn_s_sleep(1);
    }
    __syncthreads();
    // P1: load rv carry via coherent (L2-bypassing) loads
    if (tid < 256){
      const float* src = &rvs[((size_t)t*NB + b)*ND + tid];
      rv_s[tid] = (t == 0) ? *src
                : __hip_atomic_load(src, __ATOMIC_RELAXED, __HIP_MEMORY_SCOPE_AGENT);
    }
    __syncthreads();
    // P2: i = iface_t + rv@W_if_r + b_if — thread per column, lanes span 64
    //     consecutive columns of row-major Wifr -> 2 lines per wave-instr
    {
      const unsigned short* wc = Wifrb + (size_t)(part<<6)*NIF + c_out;
      const float* rp = &rv_s[part<<6];
      float a0=0.f,a1=0.f,a2=0.f,a3=0.f;
      #pragma unroll 4
      for (int e=0;e<64;e+=4){
        a0 += rp[e]   * bf2f(wc[(size_t)e*NIF]);
        a1 += rp[e+1] * bf2f(wc[(size_t)(e+1)*NIF]);
        a2 += rp[e+2] * bf2f(wc[(size_t)(e+2)*NIF]);
        a3 += rp[e+3] * bf2f(wc[(size_t)(e+3)*NIF]);
      }
      part_lds[part][oc] = (a0+a1)+(a2+a3);
      if (wave == 15){  // gr scalar (col 4*ND+h), lane handles 4 e's
        const unsigned short* wg = Wifrb + 4*ND + h;
        float pg = 0.f;
        #pragma unroll
        for (int j=0;j<4;j++){
          int e = (lane<<2) + j;
          pg += rv_s[e] * bf2f(wg[(size_t)e*NIF]);
        }
        #pragma unroll
        for (int o=32;o;o>>=1) pg += __shfl_xor(pg,o);
        if (lane == 0)
          grraw_s = pg + iface[((size_t)(b*NT + t))*NIF + 4*ND + h] + b_if[4*ND + h];
      }
    }
    __syncthreads();
    if (tid < 256)
      islice[tid] = part_lds[0][tid] + part_lds[1][tid] + part_lds[2][tid] + part_lds[3][tid]
                  + iface[((size_t)(b*NT + t))*NIF + c_out] + b_if[c_out];
    __syncthreads();
    // P3: normalize keys (interleaved knrw), sigmoids
    if (wave == 0){
      float vv = islice[lane]; float ss = vv*vv;
      #pragma unroll
      for (int o=32;o;o>>=1) ss += __shfl_xor(ss,o);
      knrw[lane<<1] = vv * rsqrtf(ss + 1e-8f);
    } else if (wave == 1){
      float vv = islice[64+lane]; float ss = vv*vv;
      #pragma unroll
      for (int o=32;o;o>>=1) ss += __shfl_xor(ss,o);
      knrw[(lane<<1)+1] = vv * rsqrtf(ss + 1e-8f);
    } else if (wave == 2){
      es_s[lane] = 1.f/(1.f + __expf(-islice[192+lane]));
    } else if (wave == 3 && lane == 0){
      g_s = 1.f/(1.f + __expf(-grraw_s));
    }
    __syncthreads();
    // P4: stream sims from column-major memC — lanes adjacent in n, float2/thread
    {
      const floatx2* mc = (const floatx2*)memCB;   // [64][1024] float2
      const floatx2* kn = (const floatx2*)knrw;
      float sR0=0.f,sR1=0.f,sW0=0.f,sW1=0.f;
      #pragma unroll 8
      for (int d=0; d<64; d++){
        floatx2 kk = kn[d];
        floatx2 m2 = mc[(size_t)(d<<10) + tid];
        sR0 += m2[0]*kk[0]; sR1 += m2[1]*kk[0];
        sW0 += m2[0]*kk[1]; sW1 += m2[1]*kk[1];
      }
      float r0 = rnorm[tid<<1], r1 = rnorm[(tid<<1)+1];
      simR[tid<<1] = sR0*r0; simR[(tid<<1)+1] = sR1*r1;
      simW[tid<<1] = sW0*r0; simW[(tid<<1)+1] = sW1*r1;
    }
    __syncthreads();
    // P5: top-8 — waves 0..3: (R-lo, W-lo, R-hi, W-hi), candidates in registers,
    //     tournament tree + wave butterfly, 8 sorted rounds
    if (wave < 4){
      const float* sims = (wave & 1) ? simW : simR;
      const int base = (wave >> 1) << 10;
      float cand[16];
      #pragma unroll
      for (int i=0;i<16;i++) cand[i] = sims[base + lane + (i<<6)];
      #pragma unroll
      for (int rr=0;rr<8;rr++){
        float v8[8]; int j8[8];
        #pragma unroll
        for (int i=0;i<8;i++){
          bool gsel = cand[2*i+1] > cand[2*i];
          v8[i] = gsel ? cand[2*i+1] : cand[2*i];
          j8[i] = gsel ? (2*i+1) : (2*i);
        }
        float v4[4]; int j4[4];
        #pragma unroll
        for (int i=0;i<4;i++){
          bool gsel = v8[2*i+1] > v8[2*i];
          v4[i] = gsel ? v8[2*i+1] : v8[2*i];
          j4[i] = gsel ? j8[2*i+1] : j8[2*i];
        }
        float v2[2]; int j2[2];
        #pragma unroll
        for (int i=0;i<2;i++){
          bool gsel = v4[2*i+1] > v4[2*i];
          v2[i] = gsel ? v4[2*i+1] : v4[2*i];
          j2[i] = gsel ? j4[2*i+1] : j4[2*i];
        }
        bool gsel = v2[1] > v2[0];
        float bv = gsel ? v2[1] : v2[0];
        int   bj = gsel ? j2[1] : j2[0];
        int bi = base + lane + (bj<<6);
        #pragma unroll
        for (int o=32;o;o>>=1){
          float ov = __shfl_xor(bv,o); int oi = __shfl_xor(bi,o);
          if (ov > bv || (ov == bv && oi < bi)){ bv = ov; bi = oi; }
        }
        if (lane == 0){ c8v[wave][rr] = bv; c8i[wave][rr] = bi; }
        if (lane == (bi & 63)){
          int wj = (bi >> 6) & 15;
          #pragma unroll
          for (int i=0;i<16;i++) if (i == wj) cand[i] = -1e38f;
        }
      }
    }
    __syncthreads();
    // merge two sorted top-8 halves (two-pointer) + softmax weights
    if (tid == 0 || tid == 64){
      int s2 = (tid == 0) ? 0 : 1;
      float beta = (tid == 0) ? betaR : betaW;
      const float* A  = c8v[s2];   const int* Ai  = c8i[s2];
      const float* Bv = c8v[s2+2]; const int* Bi2 = c8i[s2+2];
      int ia = 0, ib = 0;
      float mx = fmaxf(A[0], Bv[0]);
      float wsum = 0.f; float wv8[8]; int wi8[8];
      #pragma unroll
      for (int k2=0;k2<8;k2++){
        float va = A[ia], vb = Bv[ib];
        bool ta = (va > vb) || (va == vb && Ai[ia] < Bi2[ib]);
        float v = ta ? va : vb; int ix = ta ? Ai[ia] : Bi2[ib];
        if (ta) ia++; else ib++;
        float w = __expf(beta*(v - mx));
        wsum += w; wv8[k2] = w; wi8[k2] = ix;
      }
      float inv = 1.f/wsum;
      #pragma unroll
      for (int k2=0;k2<8;k2++){
        if (tid == 0){ widxR[k2] = wi8[k2]; wvalR[k2] = wv8[k2]*inv; }
        else         { widxW[k2] = wi8[k2]; wvalW[k2] = wv8[k2]*inv; }
      }
    }
    __syncthreads();
    // P6: rv_new gather from OLD mem (8 rows, row-major = coalesced); publish
    if (wave == 0){
      float acc0 = 0.f;
      #pragma unroll
      for (int j=0;j<8;j++)
        acc0 += wvalR[j] * memB[(size_t)widxR[j]*NHD + lane];
      __hip_atomic_store(&rvs[((size_t)(t+1)*NB + b)*ND + (h<<6) + lane], acc0,
                         __ATOMIC_RELAXED, __HIP_MEMORY_SCOPE_AGENT);
    }
    __syncthreads();
    // P7: sparse write update on 8 rows — updates BOTH layouts + norm cache
    if (tid < 512){
      int jr = tid >> 6, d = tid & 63;
      int n = widxW[jr]; float w = wvalW[jr];
      size_t idx = (size_t)n*NHD + d;
      float mo = memB[idx];
      float nv = mo*(1.f - w*es_s[d]) + w*(g_s*islice[128+d]);
      memB[idx] = nv;
      memCB[(size_t)(d<<11) + n] = nv;
      float ss = nv*nv;
      #pragma unroll
      for (int o=32;o;o>>=1) ss += __shfl_xor(ss,o);
      if (d == 0) rnorm[n] = rsqrtf(ss + 1e-8f);
    }
    __syncthreads();
    // P8: signal rv[t+1] ready. tid 0 is lane 0 of wave 0: its vmcnt covers the
    // wave-wide atomic stores of P6 (already at coherence point -> no cache ops).
    if (tid == 0){
      asm volatile("s_waitcnt vmcnt(0)" ::: "memory");
      __hip_atomic_fetch_add(&flags[(size_t)(t+1)*NB + b], 1u,
                             __ATOMIC_RELAXED, __HIP_MEMORY_SCOPE_AGENT);
    }
    // next-iteration poll (tid 0) includes own arrival; __syncthreads after the
    // poll orders the rest of the block.
  }
}

// build A = [hf_bf16 | rv_bf16] rows (b*256+t), K=768
__global__ __launch_bounds__(256)
void k_abig(const unsigned short* __restrict__ hb, const float* __restrict__ rvs,
            unsigned short* __restrict__ ab)
{
  int row = blockIdx.x; int b = row >> 8, t = row & 255;
  #pragma unroll
  for (int j=0;j<3;j++){
    int col = threadIdx.x + (j<<8);
    unsigned short v;
    if (col < NE) v = hb[(size_t)row*NE + col];
    else v = f2bf(rvs[((size_t)t*NB + b)*ND + (col-NE)]);
    ab[(size_t)row*768 + col] = v;
  }
}

extern "C" void kernel_launch(void* const* d_in, const int* in_sizes, int n_in,
                              void* d_out, int out_size, void* d_ws, size_t ws_size,
                              hipStream_t stream)
{
  (void)in_sizes; (void)n_in; (void)out_size; (void)ws_size;
  const int*   ids   = (const int*)  d_in[0];
  const float* emb   = (const float*)d_in[1];
  const float* pos   = (const float*)d_in[2];
  const float* ln1g  = (const float*)d_in[3];
  const float* ln1b  = (const float*)d_in[4];
  const float* ln2g  = (const float*)d_in[5];
  const float* ln2b  = (const float*)d_in[6];
  const float* Wq    = (const float*)d_in[7];
  const float* Wk    = (const float*)d_in[8];
  const float* Wv    = (const float*)d_in[9];
  const float* Wo    = (const float*)d_in[10];
  const float* W1    = (const float*)d_in[11];
  const float* b1    = (const float*)d_in[12];
  const float* W2    = (const float*)d_in[13];
  const float* b2    = (const float*)d_in[14];
  const float* lnfg  = (const float*)d_in[15];
  const float* lnfb  = (const float*)d_in[16];
  const float* Wifh  = (const float*)d_in[17];
  const float* WifrF = (const float*)d_in[18];
  const float* bif   = (const float*)d_in[19];
  const float* Wlgh  = (const float*)d_in[20];
  const float* Wlgr  = (const float*)d_in[21];
  const float* blg   = (const float*)d_in[22];
  const float* betaR = (const float*)d_in[23];
  const float* betaW = (const float*)d_in[24];
  const float* memi  = (const float*)d_in[25];
  float* out = (float*)d_out;
  char* ws = (char*)d_ws;

  size_t off = 0;
  auto alloc = [&](size_t bytes)->char*{
    char* p = ws + off;
    off = (off + bytes + 255) & ~(size_t)255;
    return p;
  };
  unsigned short* BTqkv = (unsigned short*)alloc((size_t)NL*1536*512*2);
  unsigned short* BTo   = (unsigned short*)alloc((size_t)NL*512*512*2);
  unsigned short* BT1   = (unsigned short*)alloc((size_t)NL*2048*512*2);
  unsigned short* BT2   = (unsigned short*)alloc((size_t)NL*512*2048*2);
  unsigned short* BTif  = (unsigned short*)alloc((size_t)1028*512*2);
  unsigned short* BTlm  = (unsigned short*)alloc((size_t)32000*768*2);
  unsigned short* Wifrb = (unsigned short*)alloc((size_t)256*1028*2);   // row-major [e][c]
  float* xbuf  = (float*)alloc((size_t)NMT*NE*4);
  unsigned short* hb  = (unsigned short*)alloc((size_t)NMT*NE*2);
  float* qkvb  = (float*)alloc((size_t)NMT*1536*4);
  unsigned short* ob  = (unsigned short*)alloc((size_t)NMT*NE*2);
  unsigned short* f1b = (unsigned short*)alloc((size_t)NMT*NF*2);
  float* ifb   = (float*)alloc((size_t)NMT*NIF*4);
  float* rvs   = (float*)alloc((size_t)(NT+1)*NB*ND*4);
  float* memst = (float*)alloc((size_t)NB*NHM*NN*NHD*4);
  float* memC  = (float*)alloc((size_t)NB*NHM*NN*NHD*4);
  unsigned short* abig = (unsigned short*)alloc((size_t)NMT*768*2);
  unsigned int* flags = (unsigned int*)alloc(16384);   // (NT+1)*NB arrival counters

  // ---- weight prep (transpose + bf16) ----
  for (int l=0;l<NL;l++){
    k_tcvt<<<dim3(16,16),256,0,stream>>>(Wq + (size_t)l*NE*NE, NE, NE, BTqkv + (size_t)l*1536*512,            512);
    k_tcvt<<<dim3(16,16),256,0,stream>>>(Wk + (size_t)l*NE*NE, NE, NE, BTqkv + (size_t)l*1536*512 + 512*512,  512);
    k_tcvt<<<dim3(16,16),256,0,stream>>>(Wv + (size_t)l*NE*NE, NE, NE, BTqkv + (size_t)l*1536*512 + 2*512*512,512);
    k_tcvt<<<dim3(16,16),256,0,stream>>>(Wo + (size_t)l*NE*NE, NE, NE, BTo + (size_t)l*512*512, 512);
    k_tcvt<<<dim3(64,16),256,0,stream>>>(W1 + (size_t)l*NE*NF, NE, NF, BT1 + (size_t)l*2048*512, 512);
    k_tcvt<<<dim3(16,64),256,0,stream>>>(W2 + (size_t)l*NF*NE, NF, NE, BT2 + (size_t)l*512*2048, 2048);
  }
  k_tcvt<<<dim3(33,16),256,0,stream>>>(Wifh, NE, NIF, BTif, 512);
  k_tcvt<<<dim3(1000,16),256,0,stream>>>(Wlgh, NE, NV, BTlm, 768);
  k_tcvt<<<dim3(1000,8),256,0,stream>>>(Wlgr, ND, NV, BTlm + 512, 768);
  // plain bf16 convert of W_if_r (row-major [256][1028])
  k_cvt<<<dim3((256*1028+255)/256),256,0,stream>>>(WifrF, Wifrb, 256*1028);

  hipMemsetAsync(flags, 0, 16384, stream);
  hipMemsetAsync(rvs, 0, (size_t)NB*ND*4, stream);

  k_embed<<<dim3((NMT*NE)/256),256,0,stream>>>(ids, emb, pos, xbuf);
  k_initmem<<<dim3((2*NB*NHM*NN*NHD)/256),256,0,stream>>>(memi, memst, memC);

  // ---- transformer ----
  for (int l=0;l<NL;l++){
    k_ln<<<dim3(NMT/4),256,0,stream>>>(xbuf, ln1g + l*NE, ln1b + l*NE, hb);
    k_gemm<<<dim3(16,12),256,0,stream>>>(hb, BTqkv + (size_t)l*1536*512, NMT, 1536, 512,
                                         qkvb, (unsigned short*)nullptr, (const float*)nullptr, (const float*)nullptr, 0);
    k_attn<<<dim3(NB*NHA*4),256,0,stream>>>(qkvb, ob);
    k_gemm<<<dim3(16,4),256,0,stream>>>(ob, BTo + (size_t)l*512*512, NMT, 512, 512,
                                        xbuf, (unsigned short*)nullptr, (const float*)nullptr, xbuf, 0);
    k_ln<<<dim3(NMT/4),256,0,stream>>>(xbuf, ln2g + l*NE, ln2b + l*NE, hb);
    k_gemm<<<dim3(16,16),256,0,stream>>>(hb, BT1 + (size_t)l*2048*512, NMT, 2048, 512,
                                         (float*)nullptr, f1b, b1 + l*NF, (const float*)nullptr, 1);
    k_gemm<<<dim3(16,4),256,0,stream>>>(f1b, BT2 + (size_t)l*512*2048, NMT, 512, 2048,
                                        xbuf, (unsigned short*)nullptr, b2 + l*NE, xbuf, 0);
  }
  k_ln<<<dim3(NMT/4),256,0,stream>>>(xbuf, lnfg, lnfb, hb);
  k_gemm<<<dim3(16,9),256,0,stream>>>(hb, BTif, NMT, NIF, 512,
                                      ifb, (unsigned short*)nullptr, (const float*)nullptr, (const float*)nullptr, 0);
  // ---- memory scan (single persistent kernel, 1024 threads/block, fence-free) ----
  k_scan<<<dim3(NB*NHM),1024,0,stream>>>(ifb, Wifrb, bif, betaR, betaW, memst, memC, rvs, flags);
  // ---- fused LM head: out = hf@W_lg_h + b_lg + rv@W_lg_r ----
  k_abig<<<dim3(NMT),256,0,stream>>>(hb, rvs, abig);
  k_gemm<<<dim3(16,250),256,0,stream>>>(abig, BTlm, NMT, NV, 768,
                                        out, (unsigned short*)nullptr, blg, (const float*)nullptr, 0);
}